// Round 13
// baseline (209.709 us; speedup 1.0000x reference)
//
#include <hip/hip_runtime.h>
#include <stdint.h>

// CustomMultiHeadAttention: B=2, S=4096, E=512, H=8, Dh=64, fp32 in/out.
// bf16 MFMA pipeline. ws layout (34 MB):
//   [0,    8 MB)  xb  : x as bf16 [8192][512]  (reused as attn output)
//   [8,   10 MB)  Wt  : Wq,Wk,Wv,Wo transposed bf16 [4][512 n][512 k]
//   [10,  18 MB)  Qb  : bf16 [8192][512]  (pre-scaled by log2(e)/sqrt(64))
//   [18,  26 MB)  Kb  : bf16 [8192][512]
//   [26,  34 MB)  Vtb : bf16 [b*512 + h*64 + d][4096 s]  (V transposed, columns
//                       sigma-PRE-PERMUTED within each 32-kv block so attn A-frags
//                       are contiguous 16B: pos = pi^-1(s) with
//                       pi(l = hi*8+j) = 16*(j>>2) + hi*4 + (j&3))

typedef __bf16 bf16_t;
typedef bf16_t bf16x8 __attribute__((ext_vector_type(8)));
typedef float f32x4 __attribute__((ext_vector_type(4)));
typedef unsigned short u16;
typedef unsigned int u32;

__device__ __forceinline__ u16 f2bf(float f) {
  return __builtin_bit_cast(u16, (bf16_t)f);
}

// async global->LDS, 16B per lane; LDS dest must be uniform-base + lane*16
__device__ __forceinline__ void gll16(const void* g, void* l) {
  __builtin_amdgcn_global_load_lds((__attribute__((address_space(1))) void*)(void*)(g),
                                   (__attribute__((address_space(3))) void*)(l), 16, 0, 0);
}

__device__ __forceinline__ float fexp2(float x) {
  float r; asm("v_exp_f32 %0, %1" : "=v"(r) : "v"(x)); return r;
}
__device__ __forceinline__ u32 cvtpk(float lo, float hi) {
  u32 r; asm("v_cvt_pk_bf16_f32 %0, %1, %2" : "=v"(r) : "v"(lo), "v"(hi)); return r;
}

// ---------------- prep: fp32 -> bf16 convert ----------------
__global__ void k_convert(const float* __restrict__ x, u16* __restrict__ xb, int n4) {
  int i = blockIdx.x * blockDim.x + threadIdx.x;
  if (i >= n4) return;
  float4 v = ((const float4*)x)[i];
  ushort4 o;
  o.x = f2bf(v.x); o.y = f2bf(v.y); o.z = f2bf(v.z); o.w = f2bf(v.w);
  ((ushort4*)xb)[i] = o;
}

// ---------------- prep: W [k][n] fp32 -> Wt [n][k] bf16 ----------------
__global__ void k_transposeW(const float* __restrict__ W0, const float* __restrict__ W1,
                             const float* __restrict__ W2, const float* __restrict__ W3,
                             u16* __restrict__ Wt) {
  __shared__ float tile[64][65];
  const float* W = (blockIdx.z == 0) ? W0 : (blockIdx.z == 1) ? W1 : (blockIdx.z == 2) ? W2 : W3;
  u16* out = Wt + (size_t)blockIdx.z * (512 * 512);
  int k0 = blockIdx.x * 64, n0 = blockIdx.y * 64;
  int t = threadIdx.x;
#pragma unroll
  for (int i = 0; i < 16; ++i) {
    int idx = i * 256 + t;
    int r = idx >> 6, c = idx & 63;
    tile[r][c] = W[(size_t)(k0 + r) * 512 + n0 + c];
  }
  __syncthreads();
#pragma unroll
  for (int i = 0; i < 16; ++i) {
    int idx = i * 256 + t;
    int n = idx >> 6, k = idx & 63;
    out[(size_t)(n0 + n) * 512 + k0 + k] = f2bf(tile[k][n]);
  }
}

// ---------------- shared GEMM core (double-buffered): C[128][128] += A * Bt^T ----------------
__device__ __forceinline__ void gemm_core(const u16* __restrict__ A, const u16* __restrict__ Bt,
                                          int m0, int n0, uint8_t* lds, f32x4 (&acc)[4][4]) {
  int t = threadIdx.x;
  int lane = t & 63;
  int wid = t >> 6;
  int l15 = lane & 15, hib = (lane >> 4) * 16;
  int wm = wid >> 1, wn = wid & 1;
  const uint8_t* Ab = (const uint8_t*)A + (size_t)m0 * 1024;
  const uint8_t* Bb = (const uint8_t*)Bt + (size_t)n0 * 1024;

  auto STAGE = [&](int buf, int kk) {
    int kof = kk * 128;
    uint8_t* Al = lds + buf * 32768;
    uint8_t* Bl = Al + 16384;
#pragma unroll
    for (int r = 0; r < 4; ++r) {
      int L = r * 4096 + t * 16;
      int row = L >> 7;
      int colU = (L & 127) ^ ((row & 7) << 4);
      gll16(Ab + (size_t)row * 1024 + kof + colU, Al + L);
      gll16(Bb + (size_t)row * 1024 + kof + colU, Bl + L);
    }
  };

  STAGE(0, 0);
  asm volatile("s_waitcnt vmcnt(0)" ::: "memory");
  __builtin_amdgcn_s_barrier();

  int cur = 0;
  for (int kk = 0; kk < 8; ++kk) {
    if (kk + 1 < 8) STAGE(cur ^ 1, kk + 1);  // prefetch flies under compute
    const uint8_t* Al = lds + cur * 32768;
    const uint8_t* Bl = Al + 16384;
#pragma unroll
    for (int ks = 0; ks < 2; ++ks) {
      bf16x8 af[4], bfr[4];
#pragma unroll
      for (int mi = 0; mi < 4; ++mi) {
        int row = wm * 64 + mi * 16 + l15;
        af[mi] = *(const bf16x8*)(Al + row * 128 + ((ks * 64 + hib) ^ ((row & 7) << 4)));
      }
#pragma unroll
      for (int ni = 0; ni < 4; ++ni) {
        int row = wn * 64 + ni * 16 + l15;
        bfr[ni] = *(const bf16x8*)(Bl + row * 128 + ((ks * 64 + hib) ^ ((row & 7) << 4)));
      }
#pragma unroll
      for (int mi = 0; mi < 4; ++mi)
#pragma unroll
        for (int ni = 0; ni < 4; ++ni)
          acc[mi][ni] = __builtin_amdgcn_mfma_f32_16x16x32_bf16(af[mi], bfr[ni], acc[mi][ni], 0, 0, 0);
    }
    asm volatile("s_waitcnt vmcnt(0)" ::: "memory");  // next tile arrived
    __builtin_amdgcn_s_barrier();
    cur ^= 1;
  }
}

// ---------------- QKV projection GEMM (z: 0=Q pre-scaled, 1=K, 2=V-transposed) ----------------
__global__ __launch_bounds__(256, 2) void k_gemm_qkv(
    const u16* __restrict__ A, const u16* __restrict__ Wt,
    const float* __restrict__ bq, const float* __restrict__ bk, const float* __restrict__ bv,
    u16* __restrict__ Qo, u16* __restrict__ Ko, u16* __restrict__ Vt) {
  __shared__ uint8_t lds[65536];
  int z = blockIdx.z;
  const u16* Bt = Wt + (size_t)z * (512 * 512);
  const float* bias = (z == 0) ? bq : (z == 1) ? bk : bv;
  float qsc = (z == 0) ? 0.18033688011112042f : 1.0f;
  int m0 = blockIdx.y * 128, n0 = blockIdx.x * 128;
  int t = threadIdx.x, lane = t & 63, wid = t >> 6;
  int l15 = lane & 15;
  int wm = wid >> 1, wn = wid & 1;

  f32x4 acc[4][4] = {};
  gemm_core(A, Bt, m0, n0, lds, acc);

  if (z != 2) {
    u16* out = (z == 0) ? Qo : Ko;
#pragma unroll
    for (int mi = 0; mi < 4; ++mi)
#pragma unroll
      for (int ni = 0; ni < 4; ++ni) {
        int c = wn * 64 + ni * 16 + l15;
        float bsv = bias[n0 + c];
        int rbase = wm * 64 + mi * 16 + (lane >> 4) * 4;
#pragma unroll
        for (int i = 0; i < 4; ++i)
          *(u16*)(lds + (rbase + i) * 256 + c * 2) = f2bf((acc[mi][ni][i] + bsv) * qsc);
      }
    __syncthreads();
#pragma unroll
    for (int rr = 0; rr < 8; ++rr) {
      int L = rr * 4096 + t * 16;
      int row = L >> 8, col = L & 255;
      *(uint4*)((uint8_t*)out + (size_t)(m0 + row) * 1024 + n0 * 2 + col) = *(const uint4*)(lds + L);
    }
  } else {
#pragma unroll
    for (int mi = 0; mi < 4; ++mi)
#pragma unroll
      for (int ni = 0; ni < 4; ++ni) {
        int c = wn * 64 + ni * 16 + l15;
        float bsv = bias[n0 + c];
        int rbase = wm * 64 + mi * 16 + (lane >> 4) * 4;
#pragma unroll
        for (int i = 0; i < 4; ++i) {
          // sigma pre-permutation within each 32-kv block: pos = pi^-1(s_local)
          int sl = rbase + i;
          int t5 = sl & 31;
          int pos = (sl & ~31) | (t5 & 3) | (((t5 >> 4) & 1) << 2) | (((t5 >> 2) & 3) << 3);
          *(u16*)(lds + c * 272 + pos * 2) = f2bf(acc[mi][ni][i] + bsv);
        }
      }
    __syncthreads();
    int b = m0 >> 12, s0 = m0 & 4095;
#pragma unroll
    for (int rr = 0; rr < 8; ++rr) {
      int L = rr * 4096 + t * 16;
      int cidx = L >> 8, rb = L & 255;
      *(uint4*)((uint8_t*)Vt + (size_t)(b * 512 + n0 + cidx) * 8192 + s0 * 2 + rb) =
          *(const uint4*)(lds + cidx * 272 + rb);
    }
  }
}

// ---------------- output projection GEMM (fp32 out) ----------------
__global__ __launch_bounds__(256, 2) void k_gemm_out(
    const u16* __restrict__ A, const u16* __restrict__ Bt,
    const float* __restrict__ bias, float* __restrict__ out) {
  __shared__ uint8_t lds[65536];
  int m0 = blockIdx.y * 128, n0 = blockIdx.x * 128;
  int t = threadIdx.x, lane = t & 63, wid = t >> 6;
  int l15 = lane & 15;
  int wm = wid >> 1, wn = wid & 1;

  f32x4 acc[4][4] = {};
  gemm_core(A, Bt, m0, n0, lds, acc);

#pragma unroll
  for (int mi = 0; mi < 4; ++mi)
#pragma unroll
    for (int ni = 0; ni < 4; ++ni) {
      int c = wn * 64 + ni * 16 + l15;
      float bsv = bias[n0 + c];
      int rbase = wm * 64 + mi * 16 + (lane >> 4) * 4;
#pragma unroll
      for (int i = 0; i < 4; ++i)
        out[(size_t)(m0 + rbase + i) * 512 + n0 + c] = acc[mi][ni][i] + bsv;
    }
}

// ---------------- flash attention: kv-QUARTER waves, global-V, K-only staging ----------------
// Grid (64,16); 4 waves/block, ALL on the same 64 q rows (q0 = bx*64). Wave p = wid
// owns kv quarter [p*32, p*32+32) of each staged 128-kv K tile (full-rate K=32 PV).
// K staged kv-128 double-buffered (2 x 16KB = 32KB); V read straight from global/L2
// as contiguous 16B A-frags (Vtb columns sigma-pre-permuted at projection time).
// Softmax: exp-direct (Q pre-scaled), denominator via ones-MFMA. 4-way sequential
// LDS merge in the epilogue (aliases staging after the final barrier).
__global__ __launch_bounds__(256, 3) void k_attn(
    const u16* __restrict__ Q, const u16* __restrict__ K,
    const u16* __restrict__ Vt, u16* __restrict__ O) {
  __shared__ uint8_t lds[32768];
  int t = threadIdx.x, lane = t & 63, wid = t >> 6;
  int l15 = lane & 15, hi = lane >> 4;
  int p = wid;
  int bh = blockIdx.y, b = bh >> 3, h = bh & 7;
  int q0 = blockIdx.x * 64;

  const uint8_t* Kbase = (const uint8_t*)K + (size_t)(b * 4096) * 1024 + h * 128;
  const uint8_t* Vbase = (const uint8_t*)Vt + (size_t)(b * 512 + h * 64) * 8192;

  // Q fragments (B-operand): Q[q = q0 + qs*16 + l15][e = ks*32 + hi*8 + j]
  bf16x8 qf[4][2];
#pragma unroll
  for (int qs = 0; qs < 4; ++qs)
#pragma unroll
    for (int ks = 0; ks < 2; ++ks)
      qf[qs][ks] = *(const bf16x8*)(Q + (size_t)(b * 4096 + q0 + qs * 16 + l15) * 512 +
                                    h * 64 + ks * 32 + hi * 8);

  // ones A-fragment for the denominator MFMA (bf16 1.0 = 0x3F80)
  uint4 ou; ou.x = 0x3F803F80u; ou.y = 0x3F803F80u; ou.z = 0x3F803F80u; ou.w = 0x3F803F80u;
  const bf16x8 ones = __builtin_bit_cast(bf16x8, ou);

  f32x4 o[4][4] = {};
  f32x4 oden[4] = {};

  // Stage K rows [kv0, kv0+128) only (16KB per buffer)
  auto STAGE = [&](int buf, int kt2) {
    uint8_t* Kl = lds + buf * 16384;
    int kv0 = kt2 * 128;
#pragma unroll
    for (int r = 0; r < 4; ++r) {
      int L = r * 4096 + t * 16;
      int row = L >> 7;
      int col = (L & 127) ^ ((row & 7) << 4);
      gll16(Kbase + (size_t)(kv0 + row) * 1024 + col, Kl + L);
    }
  };

  STAGE(0, 0);
  asm volatile("s_waitcnt vmcnt(0)" ::: "memory");
  __builtin_amdgcn_s_barrier();

  int cur = 0;
  for (int kt2 = 0; kt2 < 32; ++kt2) {
    if (kt2 + 1 < 32) STAGE(cur ^ 1, kt2 + 1);  // prefetch flies under compute

    const uint8_t* Kl = lds + cur * 16384;

    // V A-frags straight from global/L2 (contiguous 16B thanks to pre-permuted Vtb)
    size_t kvb = (size_t)(kt2 * 128 + p * 32 + hi * 8) * 2;
    bf16x8 va[4];
#pragma unroll
    for (int dg = 0; dg < 4; ++dg)
      va[dg] = *(const bf16x8*)(Vbase + (size_t)(dg * 16 + l15) * 8192 + kvb);

    // K fragments for this wave's kv quarter (rows p*32 + cg*16 + l15)
    bf16x8 kA[2][2];  // [ks][cg]
#pragma unroll
    for (int ks = 0; ks < 2; ++ks)
#pragma unroll
      for (int cg = 0; cg < 2; ++cg) {
        int row = p * 32 + cg * 16 + l15;
        kA[ks][cg] = *(const bf16x8*)(Kl + row * 128 + ((ks * 64 + hi * 16) ^ ((row & 7) << 4)));
      }

    // QK^T: s[qs][cg][i] = log2-domain scores (Q pre-scaled)
    f32x4 s[4][2] = {};
    __builtin_amdgcn_s_setprio(1);
#pragma unroll
    for (int qs = 0; qs < 4; ++qs)
#pragma unroll
      for (int ks = 0; ks < 2; ++ks)
#pragma unroll
        for (int cg = 0; cg < 2; ++cg)
          s[qs][cg] = __builtin_amdgcn_mfma_f32_16x16x32_bf16(kA[ks][cg], qf[qs][ks], s[qs][cg], 0, 0, 0);
    __builtin_amdgcn_s_setprio(0);

    // softmax numerators: p = exp2(s), packed straight to bf16
    bf16x8 pb[4];
#pragma unroll
    for (int qs = 0; qs < 4; ++qs) {
      float pv[8];
#pragma unroll
      for (int cg = 0; cg < 2; ++cg)
#pragma unroll
        for (int i = 0; i < 4; ++i)
          pv[cg * 4 + i] = fexp2(s[qs][cg][i]);
      uint4 pu;
      pu.x = cvtpk(pv[0], pv[1]);
      pu.y = cvtpk(pv[2], pv[3]);
      pu.z = cvtpk(pv[4], pv[5]);
      pu.w = cvtpk(pv[6], pv[7]);
      pb[qs] = __builtin_bit_cast(bf16x8, pu);
    }

    // PV (K=32, full rate) + denominator ones-MFMA
    __builtin_amdgcn_s_setprio(1);
#pragma unroll
    for (int qs = 0; qs < 4; ++qs)
      oden[qs] = __builtin_amdgcn_mfma_f32_16x16x32_bf16(ones, pb[qs], oden[qs], 0, 0, 0);
#pragma unroll
    for (int dg = 0; dg < 4; ++dg)
#pragma unroll
      for (int qs = 0; qs < 4; ++qs)
        o[qs][dg] = __builtin_amdgcn_mfma_f32_16x16x32_bf16(va[dg], pb[qs], o[qs][dg], 0, 0, 0);
    __builtin_amdgcn_s_setprio(0);

    asm volatile("s_waitcnt vmcnt(0)" ::: "memory");  // next K tile arrived
    __builtin_amdgcn_s_barrier();
    cur ^= 1;
  }

  float den[4];
#pragma unroll
  for (int qs = 0; qs < 4; ++qs) den[qs] = oden[qs][0];

  // ---- 4-way sequential merge via LDS (17KB region aliases staging) ----
  auto store_p = [&]() {
#pragma unroll
    for (int qs = 0; qs < 4; ++qs) {
#pragma unroll
      for (int dg = 0; dg < 4; ++dg)
        *(f32x4*)(lds + ((qs * 4 + dg) * 64 + lane) * 16) = o[qs][dg];
      *(float*)(lds + 16384 + (qs * 64 + lane) * 4) = den[qs];
    }
  };
  auto load_add = [&]() {
#pragma unroll
    for (int qs = 0; qs < 4; ++qs) {
#pragma unroll
      for (int dg = 0; dg < 4; ++dg)
        o[qs][dg] += *(const f32x4*)(lds + ((qs * 4 + dg) * 64 + lane) * 16);
      den[qs] += *(const float*)(lds + 16384 + (qs * 64 + lane) * 4);
    }
  };

  if (wid == 3) store_p();
  __syncthreads();
  if (wid == 2) { load_add(); store_p(); }
  __syncthreads();
  if (wid == 1) { load_add(); store_p(); }
  __syncthreads();
  if (wid == 0) {
    load_add();
#pragma unroll
    for (int qs = 0; qs < 4; ++qs) {
      float inv = 1.0f / den[qs];
#pragma unroll
      for (int dg = 0; dg < 4; ++dg) {
        ushort4 pk;
        pk.x = f2bf(o[qs][dg][0] * inv);
        pk.y = f2bf(o[qs][dg][1] * inv);
        pk.z = f2bf(o[qs][dg][2] * inv);
        pk.w = f2bf(o[qs][dg][3] * inv);
        *(uint2*)(O + (size_t)(b * 4096 + q0 + qs * 16 + l15) * 512 + h * 64 + dg * 16 + hi * 4) =
            __builtin_bit_cast(uint2, pk);
      }
    }
  }
}

extern "C" void kernel_launch(void* const* d_in, const int* in_sizes, int n_in,
                              void* d_out, int out_size, void* d_ws, size_t ws_size,
                              hipStream_t stream) {
  const float* x  = (const float*)d_in[0];
  const float* Wq = (const float*)d_in[1];
  const float* bq = (const float*)d_in[2];
  const float* Wk = (const float*)d_in[3];
  const float* bk = (const float*)d_in[4];
  const float* Wv = (const float*)d_in[5];
  const float* bv = (const float*)d_in[6];
  const float* Wo = (const float*)d_in[7];
  const float* bo = (const float*)d_in[8];
  float* out = (float*)d_out;

  uint8_t* ws = (uint8_t*)d_ws;
  u16* xb  = (u16*)(ws);                  // 8 MB; reused as attn output buffer
  u16* Wt  = (u16*)(ws + 8388608);        // 2 MB
  u16* Qb  = (u16*)(ws + 10485760);       // 8 MB
  u16* Kb  = (u16*)(ws + 18874368);       // 8 MB
  u16* Vtb = (u16*)(ws + 27262976);       // 8 MB  (total 34 MB)
  u16* attn = xb;

  k_convert<<<4096, 256, 0, stream>>>(x, xb, 1048576);
  k_transposeW<<<dim3(8, 8, 4), 256, 0, stream>>>(Wq, Wk, Wv, Wo, Wt);
  k_gemm_qkv<<<dim3(4, 64, 3), 256, 0, stream>>>(xb, Wt, bq, bk, bv, Qb, Kb, Vtb);
  k_attn<<<dim3(64, 16), 256, 0, stream>>>(Qb, Kb, Vtb, attn);
  k_gemm_out<<<dim3(4, 64), 256, 0, stream>>>(attn, Wt + 3 * 262144, bo, out);
}

// Round 14
// 117.193 us; speedup vs baseline: 1.7894x; 1.7894x over previous
//
#include <hip/hip_runtime.h>
#include <stdint.h>

// CustomMultiHeadAttention: B=2, S=4096, E=512, H=8, Dh=64, fp32 in/out.
// bf16 MFMA pipeline. ws layout (34 MB):
//   [0,    8 MB)  xb  : x as bf16 [8192][512]  (reused as attn output)
//   [8,   10 MB)  Wt  : Wq,Wk,Wv,Wo transposed bf16 [4][512 n][512 k]
//   [10,  18 MB)  Qb  : bf16 [8192][512]  (pre-scaled by log2(e)/sqrt(64))
//   [18,  26 MB)  Kb  : bf16 [8192][512]
//   [26,  34 MB)  Vtb : bf16 TILED [b*8+h][kv-block of 32][d 64][32 kv], 4KB blocks;
//                       within each 32-kv block columns are sigma-pre-permuted
//                       (r13-verified) so attn A-frags are contiguous 16B/lane and
//                       a wave's va[dg] load covers exactly 1024 contiguous bytes.

typedef __bf16 bf16_t;
typedef bf16_t bf16x8 __attribute__((ext_vector_type(8)));
typedef float f32x4 __attribute__((ext_vector_type(4)));
typedef unsigned short u16;
typedef unsigned int u32;

__device__ __forceinline__ u16 f2bf(float f) {
  return __builtin_bit_cast(u16, (bf16_t)f);
}

// async global->LDS, 16B per lane; LDS dest must be uniform-base + lane*16
__device__ __forceinline__ void gll16(const void* g, void* l) {
  __builtin_amdgcn_global_load_lds((__attribute__((address_space(1))) void*)(void*)(g),
                                   (__attribute__((address_space(3))) void*)(l), 16, 0, 0);
}

__device__ __forceinline__ float fexp2(float x) {
  float r; asm("v_exp_f32 %0, %1" : "=v"(r) : "v"(x)); return r;
}
__device__ __forceinline__ u32 cvtpk(float lo, float hi) {
  u32 r; asm("v_cvt_pk_bf16_f32 %0, %1, %2" : "=v"(r) : "v"(lo), "v"(hi)); return r;
}

// ---------------- prep: fp32 -> bf16 convert ----------------
__global__ void k_convert(const float* __restrict__ x, u16* __restrict__ xb, int n4) {
  int i = blockIdx.x * blockDim.x + threadIdx.x;
  if (i >= n4) return;
  float4 v = ((const float4*)x)[i];
  ushort4 o;
  o.x = f2bf(v.x); o.y = f2bf(v.y); o.z = f2bf(v.z); o.w = f2bf(v.w);
  ((ushort4*)xb)[i] = o;
}

// ---------------- prep: W [k][n] fp32 -> Wt [n][k] bf16 ----------------
__global__ void k_transposeW(const float* __restrict__ W0, const float* __restrict__ W1,
                             const float* __restrict__ W2, const float* __restrict__ W3,
                             u16* __restrict__ Wt) {
  __shared__ float tile[64][65];
  const float* W = (blockIdx.z == 0) ? W0 : (blockIdx.z == 1) ? W1 : (blockIdx.z == 2) ? W2 : W3;
  u16* out = Wt + (size_t)blockIdx.z * (512 * 512);
  int k0 = blockIdx.x * 64, n0 = blockIdx.y * 64;
  int t = threadIdx.x;
#pragma unroll
  for (int i = 0; i < 16; ++i) {
    int idx = i * 256 + t;
    int r = idx >> 6, c = idx & 63;
    tile[r][c] = W[(size_t)(k0 + r) * 512 + n0 + c];
  }
  __syncthreads();
#pragma unroll
  for (int i = 0; i < 16; ++i) {
    int idx = i * 256 + t;
    int n = idx >> 6, k = idx & 63;
    out[(size_t)(n0 + n) * 512 + k0 + k] = f2bf(tile[k][n]);
  }
}

// ---------------- shared GEMM core (double-buffered): C[128][128] += A * Bt^T ----------------
__device__ __forceinline__ void gemm_core(const u16* __restrict__ A, const u16* __restrict__ Bt,
                                          int m0, int n0, uint8_t* lds, f32x4 (&acc)[4][4]) {
  int t = threadIdx.x;
  int lane = t & 63;
  int wid = t >> 6;
  int l15 = lane & 15, hib = (lane >> 4) * 16;
  int wm = wid >> 1, wn = wid & 1;
  const uint8_t* Ab = (const uint8_t*)A + (size_t)m0 * 1024;
  const uint8_t* Bb = (const uint8_t*)Bt + (size_t)n0 * 1024;

  auto STAGE = [&](int buf, int kk) {
    int kof = kk * 128;
    uint8_t* Al = lds + buf * 32768;
    uint8_t* Bl = Al + 16384;
#pragma unroll
    for (int r = 0; r < 4; ++r) {
      int L = r * 4096 + t * 16;
      int row = L >> 7;
      int colU = (L & 127) ^ ((row & 7) << 4);
      gll16(Ab + (size_t)row * 1024 + kof + colU, Al + L);
      gll16(Bb + (size_t)row * 1024 + kof + colU, Bl + L);
    }
  };

  STAGE(0, 0);
  asm volatile("s_waitcnt vmcnt(0)" ::: "memory");
  __builtin_amdgcn_s_barrier();

  int cur = 0;
  for (int kk = 0; kk < 8; ++kk) {
    if (kk + 1 < 8) STAGE(cur ^ 1, kk + 1);  // prefetch flies under compute
    const uint8_t* Al = lds + cur * 32768;
    const uint8_t* Bl = Al + 16384;
#pragma unroll
    for (int ks = 0; ks < 2; ++ks) {
      bf16x8 af[4], bfr[4];
#pragma unroll
      for (int mi = 0; mi < 4; ++mi) {
        int row = wm * 64 + mi * 16 + l15;
        af[mi] = *(const bf16x8*)(Al + row * 128 + ((ks * 64 + hib) ^ ((row & 7) << 4)));
      }
#pragma unroll
      for (int ni = 0; ni < 4; ++ni) {
        int row = wn * 64 + ni * 16 + l15;
        bfr[ni] = *(const bf16x8*)(Bl + row * 128 + ((ks * 64 + hib) ^ ((row & 7) << 4)));
      }
#pragma unroll
      for (int mi = 0; mi < 4; ++mi)
#pragma unroll
        for (int ni = 0; ni < 4; ++ni)
          acc[mi][ni] = __builtin_amdgcn_mfma_f32_16x16x32_bf16(af[mi], bfr[ni], acc[mi][ni], 0, 0, 0);
    }
    asm volatile("s_waitcnt vmcnt(0)" ::: "memory");  // next tile arrived
    __builtin_amdgcn_s_barrier();
    cur ^= 1;
  }
}

// ---------------- QKV projection GEMM (z: 0=Q pre-scaled, 1=K, 2=V tiled) ----------------
__global__ __launch_bounds__(256, 2) void k_gemm_qkv(
    const u16* __restrict__ A, const u16* __restrict__ Wt,
    const float* __restrict__ bq, const float* __restrict__ bk, const float* __restrict__ bv,
    u16* __restrict__ Qo, u16* __restrict__ Ko, u16* __restrict__ Vt) {
  __shared__ uint8_t lds[65536];
  int z = blockIdx.z;
  const u16* Bt = Wt + (size_t)z * (512 * 512);
  const float* bias = (z == 0) ? bq : (z == 1) ? bk : bv;
  float qsc = (z == 0) ? 0.18033688011112042f : 1.0f;
  int m0 = blockIdx.y * 128, n0 = blockIdx.x * 128;
  int t = threadIdx.x, lane = t & 63, wid = t >> 6;
  int l15 = lane & 15;
  int wm = wid >> 1, wn = wid & 1;

  f32x4 acc[4][4] = {};
  gemm_core(A, Bt, m0, n0, lds, acc);

  if (z != 2) {
    u16* out = (z == 0) ? Qo : Ko;
#pragma unroll
    for (int mi = 0; mi < 4; ++mi)
#pragma unroll
      for (int ni = 0; ni < 4; ++ni) {
        int c = wn * 64 + ni * 16 + l15;
        float bsv = bias[n0 + c];
        int rbase = wm * 64 + mi * 16 + (lane >> 4) * 4;
#pragma unroll
        for (int i = 0; i < 4; ++i)
          *(u16*)(lds + (rbase + i) * 256 + c * 2) = f2bf((acc[mi][ni][i] + bsv) * qsc);
      }
    __syncthreads();
#pragma unroll
    for (int rr = 0; rr < 8; ++rr) {
      int L = rr * 4096 + t * 16;
      int row = L >> 8, col = L & 255;
      *(uint4*)((uint8_t*)out + (size_t)(m0 + row) * 1024 + n0 * 2 + col) = *(const uint4*)(lds + L);
    }
  } else {
#pragma unroll
    for (int mi = 0; mi < 4; ++mi)
#pragma unroll
      for (int ni = 0; ni < 4; ++ni) {
        int c = wn * 64 + ni * 16 + l15;
        float bsv = bias[n0 + c];
        int rbase = wm * 64 + mi * 16 + (lane >> 4) * 4;
#pragma unroll
        for (int i = 0; i < 4; ++i) {
          // sigma pre-permutation within each 32-kv block (r13-verified): pos = pi^-1(s)
          int sl = rbase + i;
          int t5 = sl & 31;
          int pos = (sl & ~31) | (t5 & 3) | (((t5 >> 4) & 1) << 2) | (((t5 >> 2) & 3) << 3);
          *(u16*)(lds + c * 272 + pos * 2) = f2bf(acc[mi][ni][i] + bsv);
        }
      }
    __syncthreads();
    // bulk copy into TILED layout: block kb = (s0 + rb/2)/32 holds [d 64][32 kv] (4KB)
    int b = m0 >> 12, s0 = m0 & 4095;
#pragma unroll
    for (int rr = 0; rr < 8; ++rr) {
      int L = rr * 4096 + t * 16;
      int cidx = L >> 8, rb = L & 255;
      int e = n0 + cidx, h = e >> 6, d = e & 63;
      int kb = (s0 >> 5) + (rb >> 6);
      *(uint4*)((uint8_t*)Vt + ((size_t)(b * 8 + h) * 128 + kb) * 4096 + d * 64 + (rb & 63)) =
          *(const uint4*)(lds + cidx * 272 + rb);
    }
  }
}

// ---------------- output projection GEMM (fp32 out) ----------------
__global__ __launch_bounds__(256, 2) void k_gemm_out(
    const u16* __restrict__ A, const u16* __restrict__ Bt,
    const float* __restrict__ bias, float* __restrict__ out) {
  __shared__ uint8_t lds[65536];
  int m0 = blockIdx.y * 128, n0 = blockIdx.x * 128;
  int t = threadIdx.x, lane = t & 63, wid = t >> 6;
  int l15 = lane & 15;
  int wm = wid >> 1, wn = wid & 1;

  f32x4 acc[4][4] = {};
  gemm_core(A, Bt, m0, n0, lds, acc);

#pragma unroll
  for (int mi = 0; mi < 4; ++mi)
#pragma unroll
    for (int ni = 0; ni < 4; ++ni) {
      int c = wn * 64 + ni * 16 + l15;
      float bsv = bias[n0 + c];
      int rbase = wm * 64 + mi * 16 + (lane >> 4) * 4;
#pragma unroll
      for (int i = 0; i < 4; ++i)
        out[(size_t)(m0 + rbase + i) * 512 + n0 + c] = acc[mi][ni][i] + bsv;
    }
}

// ---------------- flash attention: r12 structure, K-only LDS, tiled global-V ----------------
// Grid (32,16); 4 waves. Pair g = wid>>1 owns 64 q rows; wave p = wid&1 does kv-half
// [p*32, +32) of each 64-kv SUBTILE of a kv-128 staged K tile. V comes straight from
// L2 via the TILED Vtb: block kb = kt2*4 + sub*2 + p, va[dg] = 16B/lane, wave-contiguous
// 1KB. exp-direct softmax (Q pre-scaled) + ones-MFMA denominator. launch_bounds(256,2)
// (r13 lesson: a 3-wave cap spills the 180-reg working set to scratch, 44MB of traffic).
__global__ __launch_bounds__(256, 2) void k_attn(
    const u16* __restrict__ Q, const u16* __restrict__ K,
    const u16* __restrict__ Vt, u16* __restrict__ O) {
  __shared__ uint8_t lds[34816];
  int t = threadIdx.x, lane = t & 63, wid = t >> 6;
  int l15 = lane & 15, hi = lane >> 4;
  int g = wid >> 1, p = wid & 1;
  int bh = blockIdx.y, b = bh >> 3, h = bh & 7;
  int q0 = blockIdx.x * 128 + g * 64;

  const uint8_t* Kbase = (const uint8_t*)K + (size_t)(b * 4096) * 1024 + h * 128;
  const uint8_t* Vbase = (const uint8_t*)Vt + (size_t)(b * 8 + h) * 524288;

  // Q fragments (B-operand): Q[q = q0 + qs*16 + l15][e = ks*32 + hi*8 + j]
  bf16x8 qf[4][2];
#pragma unroll
  for (int qs = 0; qs < 4; ++qs)
#pragma unroll
    for (int ks = 0; ks < 2; ++ks)
      qf[qs][ks] = *(const bf16x8*)(Q + (size_t)(b * 4096 + q0 + qs * 16 + l15) * 512 +
                                    h * 64 + ks * 32 + hi * 8);

  // ones A-fragment for the denominator MFMA (bf16 1.0 = 0x3F80)
  uint4 ou; ou.x = 0x3F803F80u; ou.y = 0x3F803F80u; ou.z = 0x3F803F80u; ou.w = 0x3F803F80u;
  const bf16x8 ones = __builtin_bit_cast(bf16x8, ou);

  f32x4 o[4][4] = {};
  f32x4 oden[4] = {};

  // Stage K rows [kv0, kv0+128) only (16KB per buffer)
  auto STAGE = [&](int buf, int kt2) {
    uint8_t* Kl = lds + buf * 16384;
    int kv0 = kt2 * 128;
#pragma unroll
    for (int r = 0; r < 4; ++r) {
      int L = r * 4096 + t * 16;
      int row = L >> 7;
      int col = (L & 127) ^ ((row & 7) << 4);
      gll16(Kbase + (size_t)(kv0 + row) * 1024 + col, Kl + L);
    }
  };

  STAGE(0, 0);
  asm volatile("s_waitcnt vmcnt(0)" ::: "memory");
  __builtin_amdgcn_s_barrier();

  int cur = 0;
  for (int kt2 = 0; kt2 < 32; ++kt2) {
    if (kt2 + 1 < 32) STAGE(cur ^ 1, kt2 + 1);  // prefetch flies under 2 subtiles

    const uint8_t* Kbuf = lds + cur * 16384;

#pragma unroll
    for (int sub = 0; sub < 2; ++sub) {
      const uint8_t* Kl = Kbuf + sub * 8192;

      // V A-frags from L2 (tiled, wave-contiguous 1KB per dg); issued early so the
      // QK^T + softmax below hides the latency
      int kb = kt2 * 4 + sub * 2 + p;
      bf16x8 va[4];
#pragma unroll
      for (int dg = 0; dg < 4; ++dg)
        va[dg] = *(const bf16x8*)(Vbase + (size_t)kb * 4096 + (dg * 16 + l15) * 64 + hi * 16);

      // K fragments for this wave's kv half (rows p*32 + cg*16 + l15)
      bf16x8 kA[2][2];  // [ks][cg]
#pragma unroll
      for (int ks = 0; ks < 2; ++ks)
#pragma unroll
        for (int cg = 0; cg < 2; ++cg) {
          int row = p * 32 + cg * 16 + l15;
          kA[ks][cg] = *(const bf16x8*)(Kl + row * 128 + ((ks * 64 + hi * 16) ^ ((row & 7) << 4)));
        }

      // QK^T: s[qs][cg][i] = log2-domain scores (Q pre-scaled)
      f32x4 s[4][2] = {};
      __builtin_amdgcn_s_setprio(1);
#pragma unroll
      for (int qs = 0; qs < 4; ++qs)
#pragma unroll
        for (int ks = 0; ks < 2; ++ks)
#pragma unroll
          for (int cg = 0; cg < 2; ++cg)
            s[qs][cg] = __builtin_amdgcn_mfma_f32_16x16x32_bf16(kA[ks][cg], qf[qs][ks], s[qs][cg], 0, 0, 0);
      __builtin_amdgcn_s_setprio(0);

      // softmax numerators: p = exp2(s), packed straight to bf16
      bf16x8 pb[4];
#pragma unroll
      for (int qs = 0; qs < 4; ++qs) {
        float pv[8];
#pragma unroll
        for (int cg = 0; cg < 2; ++cg)
#pragma unroll
          for (int i = 0; i < 4; ++i)
            pv[cg * 4 + i] = fexp2(s[qs][cg][i]);
        uint4 pu;
        pu.x = cvtpk(pv[0], pv[1]);
        pu.y = cvtpk(pv[2], pv[3]);
        pu.z = cvtpk(pv[4], pv[5]);
        pu.w = cvtpk(pv[6], pv[7]);
        pb[qs] = __builtin_bit_cast(bf16x8, pu);
      }

      // PV (K=32) + denominator ones-MFMA
      __builtin_amdgcn_s_setprio(1);
#pragma unroll
      for (int qs = 0; qs < 4; ++qs)
        oden[qs] = __builtin_amdgcn_mfma_f32_16x16x32_bf16(ones, pb[qs], oden[qs], 0, 0, 0);
#pragma unroll
      for (int dg = 0; dg < 4; ++dg)
#pragma unroll
        for (int qs = 0; qs < 4; ++qs)
          o[qs][dg] = __builtin_amdgcn_mfma_f32_16x16x32_bf16(va[dg], pb[qs], o[qs][dg], 0, 0, 0);
      __builtin_amdgcn_s_setprio(0);
    }

    asm volatile("s_waitcnt vmcnt(0)" ::: "memory");  // next K tile arrived
    __builtin_amdgcn_s_barrier();
    cur ^= 1;
  }

  // denominators: every lane holds the full half-range sum for q = l15 (+qs*16)
  float den[4];
#pragma unroll
  for (int qs = 0; qs < 4; ++qs) den[qs] = oden[qs][0];

  // ---- merge the two kv-halves of each pair via LDS (17 KB region per pair; aliases
  //      staging buffers, safe after the final barrier) ----
  uint8_t* base = lds + g * 17408;
  if (p) {
#pragma unroll
    for (int qs = 0; qs < 4; ++qs) {
#pragma unroll
      for (int dg = 0; dg < 4; ++dg)
        *(f32x4*)(base + ((qs * 4 + dg) * 64 + lane) * 16) = o[qs][dg];
      *(float*)(base + 16384 + (qs * 64 + lane) * 4) = den[qs];
    }
  }
  __syncthreads();
  if (!p) {
#pragma unroll
    for (int qs = 0; qs < 4; ++qs) {
      float pl = *(const float*)(base + 16384 + (qs * 64 + lane) * 4);
      float inv = 1.0f / (den[qs] + pl);
#pragma unroll
      for (int dg = 0; dg < 4; ++dg) {
        f32x4 po = *(const f32x4*)(base + ((qs * 4 + dg) * 64 + lane) * 16);
        ushort4 pk;
        pk.x = f2bf((o[qs][dg][0] + po[0]) * inv);
        pk.y = f2bf((o[qs][dg][1] + po[1]) * inv);
        pk.z = f2bf((o[qs][dg][2] + po[2]) * inv);
        pk.w = f2bf((o[qs][dg][3] + po[3]) * inv);
        *(uint2*)(O + (size_t)(b * 4096 + q0 + qs * 16 + l15) * 512 + h * 64 + dg * 16 + hi * 4) =
            __builtin_bit_cast(uint2, pk);
      }
    }
  }
}

extern "C" void kernel_launch(void* const* d_in, const int* in_sizes, int n_in,
                              void* d_out, int out_size, void* d_ws, size_t ws_size,
                              hipStream_t stream) {
  const float* x  = (const float*)d_in[0];
  const float* Wq = (const float*)d_in[1];
  const float* bq = (const float*)d_in[2];
  const float* Wk = (const float*)d_in[3];
  const float* bk = (const float*)d_in[4];
  const float* Wv = (const float*)d_in[5];
  const float* bv = (const float*)d_in[6];
  const float* Wo = (const float*)d_in[7];
  const float* bo = (const float*)d_in[8];
  float* out = (float*)d_out;

  uint8_t* ws = (uint8_t*)d_ws;
  u16* xb  = (u16*)(ws);                  // 8 MB; reused as attn output buffer
  u16* Wt  = (u16*)(ws + 8388608);        // 2 MB
  u16* Qb  = (u16*)(ws + 10485760);       // 8 MB
  u16* Kb  = (u16*)(ws + 18874368);       // 8 MB
  u16* Vtb = (u16*)(ws + 27262976);       // 8 MB  (total 34 MB)
  u16* attn = xb;

  k_convert<<<4096, 256, 0, stream>>>(x, xb, 1048576);
  k_transposeW<<<dim3(8, 8, 4), 256, 0, stream>>>(Wq, Wk, Wv, Wo, Wt);
  k_gemm_qkv<<<dim3(4, 64, 3), 256, 0, stream>>>(xb, Wt, bq, bk, bv, Qb, Kb, Vtb);
  k_attn<<<dim3(32, 16), 256, 0, stream>>>(Qb, Kb, Vtb, attn);
  k_gemm_out<<<dim3(4, 64), 256, 0, stream>>>(attn, Wt + 3 * 262144, bo, out);
}

// Round 15
// 116.662 us; speedup vs baseline: 1.7976x; 1.0046x over previous
//
#include <hip/hip_runtime.h>
#include <stdint.h>

// CustomMultiHeadAttention: B=2, S=4096, E=512, H=8, Dh=64, fp32 in/out.
// bf16 MFMA pipeline. ws layout (34 MB):
//   [0,    8 MB)  xb  : x as bf16 [8192][512]  (reused as attn output)
//   [8,   10 MB)  Wt  : Wq,Wk,Wv,Wo transposed bf16 [4][512 n][512 k]
//   [10,  18 MB)  Qb  : bf16 [8192][512]  (pre-scaled by log2(e)/sqrt(64))
//   [18,  26 MB)  Kb  : bf16 [8192][512]
//   [26,  34 MB)  Vtb : bf16 TILED [b*8+h][kv-block of 32][d 64][32 kv], 4KB blocks;
//                       columns sigma-pre-permuted within each 32-kv block
//                       (r13/r14-verified) so attn A-frags are contiguous 16B/lane.

typedef __bf16 bf16_t;
typedef bf16_t bf16x8 __attribute__((ext_vector_type(8)));
typedef float f32x4 __attribute__((ext_vector_type(4)));
typedef unsigned short u16;
typedef unsigned int u32;

__device__ __forceinline__ u16 f2bf(float f) {
  return __builtin_bit_cast(u16, (bf16_t)f);
}

// async global->LDS, 16B per lane; LDS dest must be uniform-base + lane*16
__device__ __forceinline__ void gll16(const void* g, void* l) {
  __builtin_amdgcn_global_load_lds((__attribute__((address_space(1))) void*)(void*)(g),
                                   (__attribute__((address_space(3))) void*)(l), 16, 0, 0);
}

__device__ __forceinline__ float fexp2(float x) {
  float r; asm("v_exp_f32 %0, %1" : "=v"(r) : "v"(x)); return r;
}
__device__ __forceinline__ u32 cvtpk(float lo, float hi) {
  u32 r; asm("v_cvt_pk_bf16_f32 %0, %1, %2" : "=v"(r) : "v"(lo), "v"(hi)); return r;
}

// ---------------- prep: fp32 -> bf16 convert ----------------
__global__ void k_convert(const float* __restrict__ x, u16* __restrict__ xb, int n4) {
  int i = blockIdx.x * blockDim.x + threadIdx.x;
  if (i >= n4) return;
  float4 v = ((const float4*)x)[i];
  ushort4 o;
  o.x = f2bf(v.x); o.y = f2bf(v.y); o.z = f2bf(v.z); o.w = f2bf(v.w);
  ((ushort4*)xb)[i] = o;
}

// ---------------- prep: W [k][n] fp32 -> Wt [n][k] bf16 ----------------
__global__ void k_transposeW(const float* __restrict__ W0, const float* __restrict__ W1,
                             const float* __restrict__ W2, const float* __restrict__ W3,
                             u16* __restrict__ Wt) {
  __shared__ float tile[64][65];
  const float* W = (blockIdx.z == 0) ? W0 : (blockIdx.z == 1) ? W1 : (blockIdx.z == 2) ? W2 : W3;
  u16* out = Wt + (size_t)blockIdx.z * (512 * 512);
  int k0 = blockIdx.x * 64, n0 = blockIdx.y * 64;
  int t = threadIdx.x;
#pragma unroll
  for (int i = 0; i < 16; ++i) {
    int idx = i * 256 + t;
    int r = idx >> 6, c = idx & 63;
    tile[r][c] = W[(size_t)(k0 + r) * 512 + n0 + c];
  }
  __syncthreads();
#pragma unroll
  for (int i = 0; i < 16; ++i) {
    int idx = i * 256 + t;
    int n = idx >> 6, k = idx & 63;
    out[(size_t)(n0 + n) * 512 + k0 + k] = f2bf(tile[k][n]);
  }
}

// ---------------- shared GEMM core (double-buffered): C[128][128] += A * Bt^T ----------------
__device__ __forceinline__ void gemm_core(const u16* __restrict__ A, const u16* __restrict__ Bt,
                                          int m0, int n0, uint8_t* lds, f32x4 (&acc)[4][4]) {
  int t = threadIdx.x;
  int lane = t & 63;
  int wid = t >> 6;
  int l15 = lane & 15, hib = (lane >> 4) * 16;
  int wm = wid >> 1, wn = wid & 1;
  const uint8_t* Ab = (const uint8_t*)A + (size_t)m0 * 1024;
  const uint8_t* Bb = (const uint8_t*)Bt + (size_t)n0 * 1024;

  auto STAGE = [&](int buf, int kk) {
    int kof = kk * 128;
    uint8_t* Al = lds + buf * 32768;
    uint8_t* Bl = Al + 16384;
#pragma unroll
    for (int r = 0; r < 4; ++r) {
      int L = r * 4096 + t * 16;
      int row = L >> 7;
      int colU = (L & 127) ^ ((row & 7) << 4);
      gll16(Ab + (size_t)row * 1024 + kof + colU, Al + L);
      gll16(Bb + (size_t)row * 1024 + kof + colU, Bl + L);
    }
  };

  STAGE(0, 0);
  asm volatile("s_waitcnt vmcnt(0)" ::: "memory");
  __builtin_amdgcn_s_barrier();

  int cur = 0;
  for (int kk = 0; kk < 8; ++kk) {
    if (kk + 1 < 8) STAGE(cur ^ 1, kk + 1);  // prefetch flies under compute
    const uint8_t* Al = lds + cur * 32768;
    const uint8_t* Bl = Al + 16384;
#pragma unroll
    for (int ks = 0; ks < 2; ++ks) {
      bf16x8 af[4], bfr[4];
#pragma unroll
      for (int mi = 0; mi < 4; ++mi) {
        int row = wm * 64 + mi * 16 + l15;
        af[mi] = *(const bf16x8*)(Al + row * 128 + ((ks * 64 + hib) ^ ((row & 7) << 4)));
      }
#pragma unroll
      for (int ni = 0; ni < 4; ++ni) {
        int row = wn * 64 + ni * 16 + l15;
        bfr[ni] = *(const bf16x8*)(Bl + row * 128 + ((ks * 64 + hib) ^ ((row & 7) << 4)));
      }
#pragma unroll
      for (int mi = 0; mi < 4; ++mi)
#pragma unroll
        for (int ni = 0; ni < 4; ++ni)
          acc[mi][ni] = __builtin_amdgcn_mfma_f32_16x16x32_bf16(af[mi], bfr[ni], acc[mi][ni], 0, 0, 0);
    }
    asm volatile("s_waitcnt vmcnt(0)" ::: "memory");  // next tile arrived
    __builtin_amdgcn_s_barrier();
    cur ^= 1;
  }
}

// ---------------- QKV projection GEMM (z: 0=Q pre-scaled, 1=K, 2=V tiled) ----------------
__global__ __launch_bounds__(256, 2) void k_gemm_qkv(
    const u16* __restrict__ A, const u16* __restrict__ Wt,
    const float* __restrict__ bq, const float* __restrict__ bk, const float* __restrict__ bv,
    u16* __restrict__ Qo, u16* __restrict__ Ko, u16* __restrict__ Vt) {
  __shared__ uint8_t lds[65536];
  int z = blockIdx.z;
  const u16* Bt = Wt + (size_t)z * (512 * 512);
  const float* bias = (z == 0) ? bq : (z == 1) ? bk : bv;
  float qsc = (z == 0) ? 0.18033688011112042f : 1.0f;
  int m0 = blockIdx.y * 128, n0 = blockIdx.x * 128;
  int t = threadIdx.x, lane = t & 63, wid = t >> 6;
  int l15 = lane & 15;
  int wm = wid >> 1, wn = wid & 1;

  f32x4 acc[4][4] = {};
  gemm_core(A, Bt, m0, n0, lds, acc);

  if (z != 2) {
    u16* out = (z == 0) ? Qo : Ko;
#pragma unroll
    for (int mi = 0; mi < 4; ++mi)
#pragma unroll
      for (int ni = 0; ni < 4; ++ni) {
        int c = wn * 64 + ni * 16 + l15;
        float bsv = bias[n0 + c];
        int rbase = wm * 64 + mi * 16 + (lane >> 4) * 4;
#pragma unroll
        for (int i = 0; i < 4; ++i)
          *(u16*)(lds + (rbase + i) * 256 + c * 2) = f2bf((acc[mi][ni][i] + bsv) * qsc);
      }
    __syncthreads();
#pragma unroll
    for (int rr = 0; rr < 8; ++rr) {
      int L = rr * 4096 + t * 16;
      int row = L >> 8, col = L & 255;
      *(uint4*)((uint8_t*)out + (size_t)(m0 + row) * 1024 + n0 * 2 + col) = *(const uint4*)(lds + L);
    }
  } else {
#pragma unroll
    for (int mi = 0; mi < 4; ++mi)
#pragma unroll
      for (int ni = 0; ni < 4; ++ni) {
        int c = wn * 64 + ni * 16 + l15;
        float bsv = bias[n0 + c];
        int rbase = wm * 64 + mi * 16 + (lane >> 4) * 4;
#pragma unroll
        for (int i = 0; i < 4; ++i) {
          // sigma pre-permutation within each 32-kv block (verified): pos = pi^-1(s)
          int sl = rbase + i;
          int t5 = sl & 31;
          int pos = (sl & ~31) | (t5 & 3) | (((t5 >> 4) & 1) << 2) | (((t5 >> 2) & 3) << 3);
          *(u16*)(lds + c * 272 + pos * 2) = f2bf(acc[mi][ni][i] + bsv);
        }
      }
    __syncthreads();
    // bulk copy into TILED layout: block kb holds [d 64][32 kv] (4KB)
    int b = m0 >> 12, s0 = m0 & 4095;
#pragma unroll
    for (int rr = 0; rr < 8; ++rr) {
      int L = rr * 4096 + t * 16;
      int cidx = L >> 8, rb = L & 255;
      int e = n0 + cidx, h = e >> 6, d = e & 63;
      int kb = (s0 >> 5) + (rb >> 6);
      *(uint4*)((uint8_t*)Vt + ((size_t)(b * 8 + h) * 128 + kb) * 4096 + d * 64 + (rb & 63)) =
          *(const uint4*)(lds + cidx * 272 + rb);
    }
  }
}

// ---------------- output projection GEMM (fp32 out) ----------------
__global__ __launch_bounds__(256, 2) void k_gemm_out(
    const u16* __restrict__ A, const u16* __restrict__ Bt,
    const float* __restrict__ bias, float* __restrict__ out) {
  __shared__ uint8_t lds[65536];
  int m0 = blockIdx.y * 128, n0 = blockIdx.x * 128;
  int t = threadIdx.x, lane = t & 63, wid = t >> 6;
  int l15 = lane & 15;
  int wm = wid >> 1, wn = wid & 1;

  f32x4 acc[4][4] = {};
  gemm_core(A, Bt, m0, n0, lds, acc);

#pragma unroll
  for (int mi = 0; mi < 4; ++mi)
#pragma unroll
    for (int ni = 0; ni < 4; ++ni) {
      int c = wn * 64 + ni * 16 + l15;
      float bsv = bias[n0 + c];
      int rbase = wm * 64 + mi * 16 + (lane >> 4) * 4;
#pragma unroll
      for (int i = 0; i < 4; ++i)
        out[(size_t)(m0 + rbase + i) * 512 + n0 + c] = acc[mi][ni][i] + bsv;
    }
}

// ---------------- flash attention: r14 structure + V prefetched one subtile ahead ----------------
// Grid (32,16); 4 waves. Pair g = wid>>1 owns 64 q rows; wave p = wid&1 does kv-half
// [p*32, +32) of each 64-kv SUBTILE of a kv-128 staged K tile. V comes from L2 via the
// TILED Vtb, DOUBLE-BUFFERED in registers: subtile n's va loads are issued during
// subtile n-1's compute (>=650 cy ahead) so PV never waits on L2 (r14's regression).
__global__ __launch_bounds__(256, 2) void k_attn(
    const u16* __restrict__ Q, const u16* __restrict__ K,
    const u16* __restrict__ Vt, u16* __restrict__ O) {
  __shared__ uint8_t lds[34816];
  int t = threadIdx.x, lane = t & 63, wid = t >> 6;
  int l15 = lane & 15, hi = lane >> 4;
  int g = wid >> 1, p = wid & 1;
  int bh = blockIdx.y, b = bh >> 3, h = bh & 7;
  int q0 = blockIdx.x * 128 + g * 64;

  const uint8_t* Kbase = (const uint8_t*)K + (size_t)(b * 4096) * 1024 + h * 128;
  const uint8_t* Vbase = (const uint8_t*)Vt + (size_t)(b * 8 + h) * 524288;

  // Q fragments (B-operand): Q[q = q0 + qs*16 + l15][e = ks*32 + hi*8 + j]
  bf16x8 qf[4][2];
#pragma unroll
  for (int qs = 0; qs < 4; ++qs)
#pragma unroll
    for (int ks = 0; ks < 2; ++ks)
      qf[qs][ks] = *(const bf16x8*)(Q + (size_t)(b * 4096 + q0 + qs * 16 + l15) * 512 +
                                    h * 64 + ks * 32 + hi * 8);

  // ones A-fragment for the denominator MFMA (bf16 1.0 = 0x3F80)
  uint4 ou; ou.x = 0x3F803F80u; ou.y = 0x3F803F80u; ou.z = 0x3F803F80u; ou.w = 0x3F803F80u;
  const bf16x8 ones = __builtin_bit_cast(bf16x8, ou);

  f32x4 o[4][4] = {};
  f32x4 oden[4] = {};

  // V register double-buffer: vaA = current subtile, vaB = next (and swap roles)
  bf16x8 vaA[4], vaB[4];
  auto VLOAD = [&](bf16x8 (&dst)[4], int kb) {
#pragma unroll
    for (int dg = 0; dg < 4; ++dg)
      dst[dg] = *(const bf16x8*)(Vbase + (size_t)kb * 4096 + (dg * 16 + l15) * 64 + hi * 16);
  };

  // Stage K rows [kv0, kv0+128) only (16KB per buffer)
  auto STAGE = [&](int buf, int kt2) {
    uint8_t* Kl = lds + buf * 16384;
    int kv0 = kt2 * 128;
#pragma unroll
    for (int r = 0; r < 4; ++r) {
      int L = r * 4096 + t * 16;
      int row = L >> 7;
      int col = (L & 127) ^ ((row & 7) << 4);
      gll16(Kbase + (size_t)(kv0 + row) * 1024 + col, Kl + L);
    }
  };

  // subtile body: prefetch V for kbn into vaN, compute with vaC
  auto SUBTILE = [&](const uint8_t* Kl, const bf16x8 (&vaC)[4], bf16x8 (&vaN)[4],
                     int kbn, bool pref) {
    if (pref) VLOAD(vaN, kbn);  // issued first; lands during this subtile's compute

    // K fragments for this wave's kv half (rows p*32 + cg*16 + l15)
    bf16x8 kA[2][2];  // [ks][cg]
#pragma unroll
    for (int ks = 0; ks < 2; ++ks)
#pragma unroll
      for (int cg = 0; cg < 2; ++cg) {
        int row = p * 32 + cg * 16 + l15;
        kA[ks][cg] = *(const bf16x8*)(Kl + row * 128 + ((ks * 64 + hi * 16) ^ ((row & 7) << 4)));
      }

    // QK^T: s[qs][cg][i] = log2-domain scores (Q pre-scaled)
    f32x4 s[4][2] = {};
    __builtin_amdgcn_s_setprio(1);
#pragma unroll
    for (int qs = 0; qs < 4; ++qs)
#pragma unroll
      for (int ks = 0; ks < 2; ++ks)
#pragma unroll
        for (int cg = 0; cg < 2; ++cg)
          s[qs][cg] = __builtin_amdgcn_mfma_f32_16x16x32_bf16(kA[ks][cg], qf[qs][ks], s[qs][cg], 0, 0, 0);
    __builtin_amdgcn_s_setprio(0);

    // softmax numerators: p = exp2(s), packed straight to bf16
    bf16x8 pb[4];
#pragma unroll
    for (int qs = 0; qs < 4; ++qs) {
      float pv[8];
#pragma unroll
      for (int cg = 0; cg < 2; ++cg)
#pragma unroll
        for (int i = 0; i < 4; ++i)
          pv[cg * 4 + i] = fexp2(s[qs][cg][i]);
      uint4 pu;
      pu.x = cvtpk(pv[0], pv[1]);
      pu.y = cvtpk(pv[2], pv[3]);
      pu.z = cvtpk(pv[4], pv[5]);
      pu.w = cvtpk(pv[6], pv[7]);
      pb[qs] = __builtin_bit_cast(bf16x8, pu);
    }

    // PV (K=32) + denominator ones-MFMA, using the PREFETCHED vaC
    __builtin_amdgcn_s_setprio(1);
#pragma unroll
    for (int qs = 0; qs < 4; ++qs)
      oden[qs] = __builtin_amdgcn_mfma_f32_16x16x32_bf16(ones, pb[qs], oden[qs], 0, 0, 0);
#pragma unroll
    for (int dg = 0; dg < 4; ++dg)
#pragma unroll
      for (int qs = 0; qs < 4; ++qs)
        o[qs][dg] = __builtin_amdgcn_mfma_f32_16x16x32_bf16(vaC[dg], pb[qs], o[qs][dg], 0, 0, 0);
    __builtin_amdgcn_s_setprio(0);
  };

  VLOAD(vaA, p);          // subtile n=0 (kb = 2*0 + p)
  STAGE(0, 0);
  asm volatile("s_waitcnt vmcnt(0)" ::: "memory");
  __builtin_amdgcn_s_barrier();

  int cur = 0;
  for (int kt2 = 0; kt2 < 32; ++kt2) {
    if (kt2 + 1 < 32) STAGE(cur ^ 1, kt2 + 1);  // K prefetch flies under 2 subtiles

    const uint8_t* Kbuf = lds + cur * 16384;

    // sub=0 (n = 2*kt2): compute with vaA, prefetch n+1 (kb = 2*(2kt2+1)+p) into vaB
    SUBTILE(Kbuf, vaA, vaB, 2 * (2 * kt2 + 1) + p, true);
    // sub=1 (n = 2*kt2+1): compute with vaB, prefetch next tile's sub=0 into vaA
    SUBTILE(Kbuf + 8192, vaB, vaA, 2 * (2 * kt2 + 2) + p, kt2 + 1 < 32);

    asm volatile("s_waitcnt vmcnt(0)" ::: "memory");  // next K tile arrived
    __builtin_amdgcn_s_barrier();
    cur ^= 1;
  }

  // denominators: every lane holds the full half-range sum for q = l15 (+qs*16)
  float den[4];
#pragma unroll
  for (int qs = 0; qs < 4; ++qs) den[qs] = oden[qs][0];

  // ---- merge the two kv-halves of each pair via LDS (17 KB region per pair; aliases
  //      staging buffers, safe after the final barrier) ----
  uint8_t* base = lds + g * 17408;
  if (p) {
#pragma unroll
    for (int qs = 0; qs < 4; ++qs) {
#pragma unroll
      for (int dg = 0; dg < 4; ++dg)
        *(f32x4*)(base + ((qs * 4 + dg) * 64 + lane) * 16) = o[qs][dg];
      *(float*)(base + 16384 + (qs * 64 + lane) * 4) = den[qs];
    }
  }
  __syncthreads();
  if (!p) {
#pragma unroll
    for (int qs = 0; qs < 4; ++qs) {
      float pl = *(const float*)(base + 16384 + (qs * 64 + lane) * 4);
      float inv = 1.0f / (den[qs] + pl);
#pragma unroll
      for (int dg = 0; dg < 4; ++dg) {
        f32x4 po = *(const f32x4*)(base + ((qs * 4 + dg) * 64 + lane) * 16);
        ushort4 pk;
        pk.x = f2bf((o[qs][dg][0] + po[0]) * inv);
        pk.y = f2bf((o[qs][dg][1] + po[1]) * inv);
        pk.z = f2bf((o[qs][dg][2] + po[2]) * inv);
        pk.w = f2bf((o[qs][dg][3] + po[3]) * inv);
        *(uint2*)(O + (size_t)(b * 4096 + q0 + qs * 16 + l15) * 512 + h * 64 + dg * 16 + hi * 4) =
            __builtin_bit_cast(uint2, pk);
      }
    }
  }
}

extern "C" void kernel_launch(void* const* d_in, const int* in_sizes, int n_in,
                              void* d_out, int out_size, void* d_ws, size_t ws_size,
                              hipStream_t stream) {
  const float* x  = (const float*)d_in[0];
  const float* Wq = (const float*)d_in[1];
  const float* bq = (const float*)d_in[2];
  const float* Wk = (const float*)d_in[3];
  const float* bk = (const float*)d_in[4];
  const float* Wv = (const float*)d_in[5];
  const float* bv = (const float*)d_in[6];
  const float* Wo = (const float*)d_in[7];
  const float* bo = (const float*)d_in[8];
  float* out = (float*)d_out;

  uint8_t* ws = (uint8_t*)d_ws;
  u16* xb  = (u16*)(ws);                  // 8 MB; reused as attn output buffer
  u16* Wt  = (u16*)(ws + 8388608);        // 2 MB
  u16* Qb  = (u16*)(ws + 10485760);       // 8 MB
  u16* Kb  = (u16*)(ws + 18874368);       // 8 MB
  u16* Vtb = (u16*)(ws + 27262976);       // 8 MB  (total 34 MB)
  u16* attn = xb;

  k_convert<<<4096, 256, 0, stream>>>(x, xb, 1048576);
  k_transposeW<<<dim3(8, 8, 4), 256, 0, stream>>>(Wq, Wk, Wv, Wo, Wt);
  k_gemm_qkv<<<dim3(4, 64, 3), 256, 0, stream>>>(xb, Wt, bq, bk, bv, Qb, Kb, Vtb);
  k_attn<<<dim3(32, 16), 256, 0, stream>>>(Qb, Kb, Vtb, attn);
  k_gemm_out<<<dim3(4, 64), 256, 0, stream>>>(attn, Wt + 3 * 262144, bo, out);
}

// Round 16
// 115.097 us; speedup vs baseline: 1.8220x; 1.0136x over previous
//
#include <hip/hip_runtime.h>
#include <stdint.h>

// CustomMultiHeadAttention: B=2, S=4096, E=512, H=8, Dh=64, fp32 in/out.
// bf16 MFMA pipeline. ws layout (34 MB):
//   [0,    8 MB)  xb  : x as bf16 [8192][512]  (reused as attn output)
//   [8,   10 MB)  Wt  : Wq,Wk,Wv,Wo transposed bf16 [4][512 n][512 k]
//   [10,  18 MB)  Qb  : bf16 [8192][512]  (pre-scaled by log2(e)/sqrt(64))
//   [18,  26 MB)  Kb  : bf16 [8192][512]
//   [26,  34 MB)  Vtb : bf16 [b*512 + h*64 + d][4096 s]  (V transposed)

typedef __bf16 bf16_t;
typedef bf16_t bf16x8 __attribute__((ext_vector_type(8)));
typedef float f32x4 __attribute__((ext_vector_type(4)));
typedef unsigned short u16;
typedef unsigned int u32;

__device__ __forceinline__ u16 f2bf(float f) {
  return __builtin_bit_cast(u16, (bf16_t)f);
}

// async global->LDS, 16B per lane; LDS dest must be uniform-base + lane*16
__device__ __forceinline__ void gll16(const void* g, void* l) {
  __builtin_amdgcn_global_load_lds((__attribute__((address_space(1))) void*)(void*)(g),
                                   (__attribute__((address_space(3))) void*)(l), 16, 0, 0);
}

__device__ __forceinline__ float fexp2(float x) {
  float r; asm("v_exp_f32 %0, %1" : "=v"(r) : "v"(x)); return r;
}
__device__ __forceinline__ u32 cvtpk(float lo, float hi) {
  u32 r; asm("v_cvt_pk_bf16_f32 %0, %1, %2" : "=v"(r) : "v"(lo), "v"(hi)); return r;
}

// ---------------- prep: fp32 -> bf16 convert ----------------
__global__ void k_convert(const float* __restrict__ x, u16* __restrict__ xb, int n4) {
  int i = blockIdx.x * blockDim.x + threadIdx.x;
  if (i >= n4) return;
  float4 v = ((const float4*)x)[i];
  ushort4 o;
  o.x = f2bf(v.x); o.y = f2bf(v.y); o.z = f2bf(v.z); o.w = f2bf(v.w);
  ((ushort4*)xb)[i] = o;
}

// ---------------- prep: W [k][n] fp32 -> Wt [n][k] bf16 ----------------
__global__ void k_transposeW(const float* __restrict__ W0, const float* __restrict__ W1,
                             const float* __restrict__ W2, const float* __restrict__ W3,
                             u16* __restrict__ Wt) {
  __shared__ float tile[64][65];
  const float* W = (blockIdx.z == 0) ? W0 : (blockIdx.z == 1) ? W1 : (blockIdx.z == 2) ? W2 : W3;
  u16* out = Wt + (size_t)blockIdx.z * (512 * 512);
  int k0 = blockIdx.x * 64, n0 = blockIdx.y * 64;
  int t = threadIdx.x;
#pragma unroll
  for (int i = 0; i < 16; ++i) {
    int idx = i * 256 + t;
    int r = idx >> 6, c = idx & 63;
    tile[r][c] = W[(size_t)(k0 + r) * 512 + n0 + c];
  }
  __syncthreads();
#pragma unroll
  for (int i = 0; i < 16; ++i) {
    int idx = i * 256 + t;
    int n = idx >> 6, k = idx & 63;
    out[(size_t)(n0 + n) * 512 + k0 + k] = f2bf(tile[k][n]);
  }
}

// ---------------- shared GEMM core (single-buffered, r11-measured-best) ----------------
__device__ __forceinline__ void gemm_core(const u16* __restrict__ A, const u16* __restrict__ Bt,
                                          int m0, int n0, uint8_t* lds, f32x4 (&acc)[4][4]) {
  int t = threadIdx.x;
  int lane = t & 63;
  int wid = t >> 6;
  int l15 = lane & 15, hib = (lane >> 4) * 16;
  int wm = wid >> 1, wn = wid & 1;
  const uint8_t* Ab = (const uint8_t*)A + (size_t)m0 * 1024;
  const uint8_t* Bb = (const uint8_t*)Bt + (size_t)n0 * 1024;
  for (int kk = 0; kk < 8; ++kk) {
    __syncthreads();
    int kof = kk * 128;
#pragma unroll
    for (int r = 0; r < 4; ++r) {
      int L = r * 4096 + t * 16;
      int row = L >> 7;
      int colU = (L & 127) ^ ((row & 7) << 4);
      gll16(Ab + (size_t)row * 1024 + kof + colU, lds + L);
      gll16(Bb + (size_t)row * 1024 + kof + colU, lds + 16384 + L);
    }
    __syncthreads();
#pragma unroll
    for (int ks = 0; ks < 2; ++ks) {
      bf16x8 af[4], bfr[4];
#pragma unroll
      for (int mi = 0; mi < 4; ++mi) {
        int row = wm * 64 + mi * 16 + l15;
        af[mi] = *(const bf16x8*)(lds + row * 128 + ((ks * 64 + hib) ^ ((row & 7) << 4)));
      }
#pragma unroll
      for (int ni = 0; ni < 4; ++ni) {
        int row = wn * 64 + ni * 16 + l15;
        bfr[ni] = *(const bf16x8*)(lds + 16384 + row * 128 + ((ks * 64 + hib) ^ ((row & 7) << 4)));
      }
#pragma unroll
      for (int mi = 0; mi < 4; ++mi)
#pragma unroll
        for (int ni = 0; ni < 4; ++ni)
          acc[mi][ni] = __builtin_amdgcn_mfma_f32_16x16x32_bf16(af[mi], bfr[ni], acc[mi][ni], 0, 0, 0);
    }
  }
  __syncthreads();
}

// ---------------- QKV projection GEMM (z: 0=Q pre-scaled, 1=K, 2=V-transposed) ----------------
__global__ __launch_bounds__(256, 3) void k_gemm_qkv(
    const u16* __restrict__ A, const u16* __restrict__ Wt,
    const float* __restrict__ bq, const float* __restrict__ bk, const float* __restrict__ bv,
    u16* __restrict__ Qo, u16* __restrict__ Ko, u16* __restrict__ Vt) {
  __shared__ uint8_t lds[34816];
  int z = blockIdx.z;
  const u16* Bt = Wt + (size_t)z * (512 * 512);
  const float* bias = (z == 0) ? bq : (z == 1) ? bk : bv;
  float qsc = (z == 0) ? 0.18033688011112042f : 1.0f;
  int m0 = blockIdx.y * 128, n0 = blockIdx.x * 128;
  int t = threadIdx.x, lane = t & 63, wid = t >> 6;
  int l15 = lane & 15;
  int wm = wid >> 1, wn = wid & 1;

  f32x4 acc[4][4] = {};
  gemm_core(A, Bt, m0, n0, lds, acc);

  if (z != 2) {
    u16* out = (z == 0) ? Qo : Ko;
#pragma unroll
    for (int mi = 0; mi < 4; ++mi)
#pragma unroll
      for (int ni = 0; ni < 4; ++ni) {
        int c = wn * 64 + ni * 16 + l15;
        float bsv = bias[n0 + c];
        int rbase = wm * 64 + mi * 16 + (lane >> 4) * 4;
#pragma unroll
        for (int i = 0; i < 4; ++i)
          *(u16*)(lds + (rbase + i) * 256 + c * 2) = f2bf((acc[mi][ni][i] + bsv) * qsc);
      }
    __syncthreads();
#pragma unroll
    for (int rr = 0; rr < 8; ++rr) {
      int L = rr * 4096 + t * 16;
      int row = L >> 8, col = L & 255;
      *(uint4*)((uint8_t*)out + (size_t)(m0 + row) * 1024 + n0 * 2 + col) = *(const uint4*)(lds + L);
    }
  } else {
#pragma unroll
    for (int mi = 0; mi < 4; ++mi)
#pragma unroll
      for (int ni = 0; ni < 4; ++ni) {
        int c = wn * 64 + ni * 16 + l15;
        float bsv = bias[n0 + c];
        int rbase = wm * 64 + mi * 16 + (lane >> 4) * 4;
#pragma unroll
        for (int i = 0; i < 4; ++i)
          *(u16*)(lds + c * 272 + (rbase + i) * 2) = f2bf(acc[mi][ni][i] + bsv);
      }
    __syncthreads();
    int b = m0 >> 12, s0 = m0 & 4095;
#pragma unroll
    for (int rr = 0; rr < 8; ++rr) {
      int L = rr * 4096 + t * 16;
      int cidx = L >> 8, rb = L & 255;
      *(uint4*)((uint8_t*)Vt + (size_t)(b * 512 + n0 + cidx) * 8192 + s0 * 2 + rb) =
          *(const uint4*)(lds + cidx * 272 + rb);
    }
  }
}

// ---------------- output projection GEMM (fp32 out, coalesced epilogue) ----------------
__global__ __launch_bounds__(256, 3) void k_gemm_out(
    const u16* __restrict__ A, const u16* __restrict__ Bt,
    const float* __restrict__ bias, float* __restrict__ out) {
  __shared__ uint8_t lds[34816];
  int m0 = blockIdx.y * 128, n0 = blockIdx.x * 128;
  int t = threadIdx.x, lane = t & 63, wid = t >> 6;
  int l15 = lane & 15;
  int wm = wid >> 1, wn = wid & 1;

  f32x4 acc[4][4] = {};
  gemm_core(A, Bt, m0, n0, lds, acc);

  // coalesced fp32 stores via LDS (528B-padded rows), two 64-row halves
#pragma unroll
  for (int half = 0; half < 2; ++half) {
    __syncthreads();
    if (wm == half) {
#pragma unroll
      for (int mi = 0; mi < 4; ++mi)
#pragma unroll
        for (int ni = 0; ni < 4; ++ni) {
          int c = wn * 64 + ni * 16 + l15;
          float bsv = bias[n0 + c];
          int rbase = mi * 16 + (lane >> 4) * 4;
#pragma unroll
          for (int i = 0; i < 4; ++i)
            *(float*)(lds + (rbase + i) * 528 + c * 4) = acc[mi][ni][i] + bsv;
        }
    }
    __syncthreads();
#pragma unroll
    for (int it = 0; it < 8; ++it) {
      int idx = it * 256 + t;
      int row = idx >> 5, c16 = idx & 31;
      *(float4*)(out + (size_t)(m0 + half * 64 + row) * 512 + n0 + c16 * 4) =
          *(const float4*)(lds + row * 528 + c16 * 16);
    }
  }
}

// ---------------- flash attention (r12-verified): q=64/wave, kv-split pairs, kv-128 staging ----
// Grid (32,16); 4 waves. Pair g = wid>>1 owns 64 q rows; wave p = wid&1 does kv-half
// [p*32, +32) of each 64-kv SUBTILE. Staging brings 128 kv per buffer
// (K [128 rows][128B] + V [2 subtiles][64 d][128B]); ONE vmcnt/barrier per 128 kv.
// exp-direct softmax (Q pre-scaled) + ones-MFMA denominator; LDS pair-merge epilogue.
__global__ __launch_bounds__(256, 2) void k_attn(
    const u16* __restrict__ Q, const u16* __restrict__ K,
    const u16* __restrict__ Vt, u16* __restrict__ O) {
  __shared__ uint8_t lds[65536];
  int t = threadIdx.x, lane = t & 63, wid = t >> 6;
  int l15 = lane & 15, hi = lane >> 4;
  int g = wid >> 1, p = wid & 1;
  int bh = blockIdx.y, b = bh >> 3, h = bh & 7;
  int q0 = blockIdx.x * 128 + g * 64;

  const uint8_t* Kbase = (const uint8_t*)K + (size_t)(b * 4096) * 1024 + h * 128;
  const uint8_t* Vbase = (const uint8_t*)Vt + (size_t)(b * 512 + h * 64) * 8192;

  // Q fragments (B-operand): Q[q = q0 + qs*16 + l15][e = ks*32 + hi*8 + j]
  bf16x8 qf[4][2];
#pragma unroll
  for (int qs = 0; qs < 4; ++qs)
#pragma unroll
    for (int ks = 0; ks < 2; ++ks)
      qf[qs][ks] = *(const bf16x8*)(Q + (size_t)(b * 4096 + q0 + qs * 16 + l15) * 512 +
                                    h * 64 + ks * 32 + hi * 8);

  // ones A-fragment for the denominator MFMA (bf16 1.0 = 0x3F80)
  uint4 ou; ou.x = 0x3F803F80u; ou.y = 0x3F803F80u; ou.z = 0x3F803F80u; ou.w = 0x3F803F80u;
  const bf16x8 ones = __builtin_bit_cast(bf16x8, ou);

  f32x4 o[4][4] = {};
  f32x4 oden[4] = {};

  // Stage 128 kv: K rows [kv0, kv0+128), V cols [kv0, kv0+128) as 2 x [64][128B]
  auto STAGE = [&](int buf, int kt2) {
    uint8_t* Kl = lds + buf * 32768;
    uint8_t* Vl = Kl + 16384;
    int kv0 = kt2 * 128;
#pragma unroll
    for (int r = 0; r < 4; ++r) {
      int L = r * 4096 + t * 16;
      int rowK = L >> 7;
      int colK = (L & 127) ^ ((rowK & 7) << 4);
      gll16(Kbase + (size_t)(kv0 + rowK) * 1024 + colK, Kl + L);
      int rowV = (L >> 7) & 63, sub = L >> 13;
      int colV = (L & 127) ^ ((rowV & 7) << 4);
      gll16(Vbase + (size_t)rowV * 8192 + (size_t)(kv0 + sub * 64) * 2 + colV, Vl + L);
    }
  };

  STAGE(0, 0);
  asm volatile("s_waitcnt vmcnt(0)" ::: "memory");
  __builtin_amdgcn_s_barrier();

  int cur = 0;
  for (int kt2 = 0; kt2 < 32; ++kt2) {
    if (kt2 + 1 < 32) STAGE(cur ^ 1, kt2 + 1);  // prefetch flies under 2 subtiles

    uint8_t* Kbuf = lds + cur * 32768;
    uint8_t* Vbuf = Kbuf + 16384;

#pragma unroll
    for (int sub = 0; sub < 2; ++sub) {
      const uint8_t* Kl = Kbuf + sub * 8192;
      const uint8_t* Vl = Vbuf + sub * 8192;

      // K fragments for this wave's kv half (rows p*32 + cg*16 + l15) -- shared by all qs
      bf16x8 kA[2][2];  // [ks][cg]
#pragma unroll
      for (int ks = 0; ks < 2; ++ks)
#pragma unroll
        for (int cg = 0; cg < 2; ++cg) {
          int row = p * 32 + cg * 16 + l15;
          kA[ks][cg] = *(const bf16x8*)(Kl + row * 128 + ((ks * 64 + hi * 16) ^ ((row & 7) << 4)));
        }

      // QK^T: s[qs][cg][i] = log2-domain scores (Q pre-scaled)
      f32x4 s[4][2] = {};
      __builtin_amdgcn_s_setprio(1);
#pragma unroll
      for (int qs = 0; qs < 4; ++qs)
#pragma unroll
        for (int ks = 0; ks < 2; ++ks)
#pragma unroll
          for (int cg = 0; cg < 2; ++cg)
            s[qs][cg] = __builtin_amdgcn_mfma_f32_16x16x32_bf16(kA[ks][cg], qf[qs][ks], s[qs][cg], 0, 0, 0);
      __builtin_amdgcn_s_setprio(0);

      // softmax numerators: p = exp2(s), packed straight to bf16
      bf16x8 pb[4];
#pragma unroll
      for (int qs = 0; qs < 4; ++qs) {
        float pv[8];
#pragma unroll
        for (int cg = 0; cg < 2; ++cg)
#pragma unroll
          for (int i = 0; i < 4; ++i)
            pv[cg * 4 + i] = fexp2(s[qs][cg][i]);
        uint4 pu;
        pu.x = cvtpk(pv[0], pv[1]);
        pu.y = cvtpk(pv[2], pv[3]);
        pu.z = cvtpk(pv[4], pv[5]);
        pu.w = cvtpk(pv[6], pv[7]);
        pb[qs] = __builtin_bit_cast(bf16x8, pu);
      }

      // PV with sigma-permuted V A-frags (shared across all qs) + denominator ones-MFMA
      __builtin_amdgcn_s_setprio(1);
#pragma unroll
      for (int qs = 0; qs < 4; ++qs)
        oden[qs] = __builtin_amdgcn_mfma_f32_16x16x32_bf16(ones, pb[qs], oden[qs], 0, 0, 0);
#pragma unroll
      for (int dg = 0; dg < 4; ++dg) {
        int row = dg * 16 + l15;
        int sw = (row & 7) << 4;
        uint2 a0 = *(const uint2*)(Vl + row * 128 + ((p * 64 + hi * 8) ^ sw));
        uint2 a1 = *(const uint2*)(Vl + row * 128 + ((p * 64 + 32 + hi * 8) ^ sw));
        uint4 vv; vv.x = a0.x; vv.y = a0.y; vv.z = a1.x; vv.w = a1.y;
        bf16x8 va = __builtin_bit_cast(bf16x8, vv);
#pragma unroll
        for (int qs = 0; qs < 4; ++qs)
          o[qs][dg] = __builtin_amdgcn_mfma_f32_16x16x32_bf16(va, pb[qs], o[qs][dg], 0, 0, 0);
      }
      __builtin_amdgcn_s_setprio(0);
    }

    asm volatile("s_waitcnt vmcnt(0)" ::: "memory");  // next 128-kv tile arrived
    __builtin_amdgcn_s_barrier();
    cur ^= 1;
  }

  // denominators: every lane holds the full half-range sum for q = l15 (+qs*16)
  float den[4];
#pragma unroll
  for (int qs = 0; qs < 4; ++qs) den[qs] = oden[qs][0];

  // ---- merge the two kv-halves of each pair via LDS (17 KB region per pair; aliases
  //      staging buffers, safe after the final barrier) ----
  uint8_t* base = lds + g * 17408;
  if (p) {
#pragma unroll
    for (int qs = 0; qs < 4; ++qs) {
#pragma unroll
      for (int dg = 0; dg < 4; ++dg)
        *(f32x4*)(base + ((qs * 4 + dg) * 64 + lane) * 16) = o[qs][dg];
      *(float*)(base + 16384 + (qs * 64 + lane) * 4) = den[qs];
    }
  }
  __syncthreads();
  if (!p) {
#pragma unroll
    for (int qs = 0; qs < 4; ++qs) {
      float pl = *(const float*)(base + 16384 + (qs * 64 + lane) * 4);
      float inv = 1.0f / (den[qs] + pl);
#pragma unroll
      for (int dg = 0; dg < 4; ++dg) {
        f32x4 po = *(const f32x4*)(base + ((qs * 4 + dg) * 64 + lane) * 16);
        ushort4 pk;
        pk.x = f2bf((o[qs][dg][0] + po[0]) * inv);
        pk.y = f2bf((o[qs][dg][1] + po[1]) * inv);
        pk.z = f2bf((o[qs][dg][2] + po[2]) * inv);
        pk.w = f2bf((o[qs][dg][3] + po[3]) * inv);
        *(uint2*)(O + (size_t)(b * 4096 + q0 + qs * 16 + l15) * 512 + h * 64 + dg * 16 + hi * 4) =
            __builtin_bit_cast(uint2, pk);
      }
    }
  }
}

extern "C" void kernel_launch(void* const* d_in, const int* in_sizes, int n_in,
                              void* d_out, int out_size, void* d_ws, size_t ws_size,
                              hipStream_t stream) {
  const float* x  = (const float*)d_in[0];
  const float* Wq = (const float*)d_in[1];
  const float* bq = (const float*)d_in[2];
  const float* Wk = (const float*)d_in[3];
  const float* bk = (const float*)d_in[4];
  const float* Wv = (const float*)d_in[5];
  const float* bv = (const float*)d_in[6];
  const float* Wo = (const float*)d_in[7];
  const float* bo = (const float*)d_in[8];
  float* out = (float*)d_out;

  uint8_t* ws = (uint8_t*)d_ws;
  u16* xb  = (u16*)(ws);                  // 8 MB; reused as attn output buffer
  u16* Wt  = (u16*)(ws + 8388608);        // 2 MB
  u16* Qb  = (u16*)(ws + 10485760);       // 8 MB
  u16* Kb  = (u16*)(ws + 18874368);       // 8 MB
  u16* Vtb = (u16*)(ws + 27262976);       // 8 MB  (total 34 MB)
  u16* attn = xb;

  k_convert<<<4096, 256, 0, stream>>>(x, xb, 1048576);
  k_transposeW<<<dim3(8, 8, 4), 256, 0, stream>>>(Wq, Wk, Wv, Wo, Wt);
  k_gemm_qkv<<<dim3(4, 64, 3), 256, 0, stream>>>(xb, Wt, bq, bk, bv, Qb, Kb, Vtb);
  k_attn<<<dim3(32, 16), 256, 0, stream>>>(Qb, Kb, Vtb, attn);
  k_gemm_out<<<dim3(4, 64), 256, 0, stream>>>(attn, Wt + 3 * 262144, bo, out);
}